// Round 1
// baseline (1188.343 us; speedup 1.0000x reference)
//
#include <hip/hip_runtime.h>
#include <math.h>

// KG-constrained attention, fp32 baseline.
// B=2, S=2048, D=1024, H=16, HD=64. All matmuls fp32 vector (no fp32 MFMA on CDNA4).
// Pipeline: gemm<scatter> x3 (QKV proj) -> flash attention w/ mask -> gemm<plain> (out proj).

#define D_EMBED 1024
#define NH      16
#define HD      64
#define BATCH   2
#define SEQ     2048
#define MTOT    (BATCH * SEQ)   // 4096

// ---------------------------------------------------------------------------
// GEMM: Y = X[M,K] @ W[K,N] + bias[N]
// BM=128, BN=64, BK=32, 256 threads, 8x4 micro-tile.
// SCATTER=1: Y is (B, NH, S, HD) layout (for Q/K/V); SCATTER=0: plain row-major.
// ---------------------------------------------------------------------------
template <int SCATTER>
__global__ __launch_bounds__(256) void gemm_f32(const float* __restrict__ X,
                                                const float* __restrict__ W,
                                                const float* __restrict__ bias,
                                                float* __restrict__ Y,
                                                int M, int N, int K) {
    __shared__ float As[32][128];  // [k][m] transposed for stride-1 m reads
    __shared__ float Bs[32][64];   // [k][n]

    const int tid = threadIdx.x;
    const int tx = tid & 15;   // n-dim, 16 threads * 4 cols = 64
    const int ty = tid >> 4;   // m-dim, 16 threads * 8 rows = 128
    const int m0 = blockIdx.y * 128;
    const int n0 = blockIdx.x * 64;

    float acc[8][4];
#pragma unroll
    for (int i = 0; i < 8; ++i)
#pragma unroll
        for (int j = 0; j < 4; ++j) acc[i][j] = 0.f;

    for (int k0 = 0; k0 < K; k0 += 32) {
        // stage A tile: 128 rows x 32 cols = 1024 float4s, 4 per thread
#pragma unroll
        for (int l = 0; l < 4; ++l) {
            int f4 = tid + l * 256;
            int row = f4 >> 3;      // 0..127
            int c4 = f4 & 7;        // 0..7
            float4 v = *(const float4*)&X[(size_t)(m0 + row) * K + k0 + c4 * 4];
            As[c4 * 4 + 0][row] = v.x;
            As[c4 * 4 + 1][row] = v.y;
            As[c4 * 4 + 2][row] = v.z;
            As[c4 * 4 + 3][row] = v.w;
        }
        // stage B tile: 32 rows x 64 cols = 512 float4s, 2 per thread
#pragma unroll
        for (int l = 0; l < 2; ++l) {
            int f4 = tid + l * 256;
            int row = f4 >> 4;      // 0..31
            int c4 = f4 & 15;       // 0..15
            float4 v = *(const float4*)&W[(size_t)(k0 + row) * N + n0 + c4 * 4];
            *(float4*)&Bs[row][c4 * 4] = v;
        }
        __syncthreads();
#pragma unroll
        for (int kk = 0; kk < 32; ++kk) {
            float a[8], b[4];
            *(float4*)&a[0] = *(const float4*)&As[kk][ty * 8];
            *(float4*)&a[4] = *(const float4*)&As[kk][ty * 8 + 4];
            *(float4*)&b[0] = *(const float4*)&Bs[kk][tx * 4];
#pragma unroll
            for (int i = 0; i < 8; ++i)
#pragma unroll
                for (int j = 0; j < 4; ++j) acc[i][j] = fmaf(a[i], b[j], acc[i][j]);
        }
        __syncthreads();
    }

    // epilogue: + bias, store
    const int n = n0 + tx * 4;
    float4 bv = *(const float4*)&bias[n];
#pragma unroll
    for (int i = 0; i < 8; ++i) {
        int m = m0 + ty * 8 + i;
        float4 v;
        v.x = acc[i][0] + bv.x;
        v.y = acc[i][1] + bv.y;
        v.z = acc[i][2] + bv.z;
        v.w = acc[i][3] + bv.w;
        if (SCATTER) {
            // (m, n) -> (b, h, s, e):  m = b*SEQ + s, n = h*HD + e
            int b = m >> 11;          // / SEQ
            int s = m & (SEQ - 1);
            int h = n >> 6;           // / HD
            int e = n & (HD - 1);
            *(float4*)&Y[(size_t)((b * NH + h) * SEQ + s) * HD + e] = v;
        } else {
            *(float4*)&Y[(size_t)m * N + n] = v;
        }
    }
}

// ---------------------------------------------------------------------------
// Flash-style masked attention, fp32.
// Grid: (SEQ/64, BATCH*NH). Block: 256 threads.
// Per block: 64 queries of one (b,h); loop over 32 key tiles of 64.
// Q,K stored [d][q] transposed in LDS; V [k][e]; P [k][q] (+1 pad).
// Masked score = -2e30 (so fully-masked tiles give p == 0 exactly with
// running max init -1e30; no inf-inf NaN path).
// ---------------------------------------------------------------------------
__global__ __launch_bounds__(256) void attn_f32(const float* __restrict__ Q,
                                                const float* __restrict__ Km,
                                                const float* __restrict__ V,
                                                const float* __restrict__ mask,
                                                float* __restrict__ O) {
    __shared__ float Qs[64][64];    // [d][q]
    __shared__ float Ks[64][64];    // [d][k]
    __shared__ float Vs[64][64];    // [k][e]
    __shared__ float Ps[64][65];    // [k][q], pad to break stride-64 banks
    __shared__ float m_run[64], l_run[64], sc_s[64];

    const int tid = threadIdx.x;
    const int tx = tid & 15;        // e / k micro dim
    const int ty = tid >> 4;        // q micro dim
    const int qt = blockIdx.x;
    const int bh = blockIdx.y;      // b*NH + h
    const int b = bh >> 4;
    const int h = bh & 15;

    const float* Qb = Q + (size_t)(bh * SEQ + qt * 64) * HD;
    const float* Kb = Km + (size_t)bh * SEQ * HD;
    const float* Vb = V + (size_t)bh * SEQ * HD;
    const float* Mb = mask + (size_t)b * SEQ * SEQ + (size_t)(qt * 64) * SEQ;

    // load Q tile transposed: Qs[d][q]
#pragma unroll
    for (int l = 0; l < 4; ++l) {
        int f4 = tid + l * 256;
        int row = f4 >> 4;          // q 0..63
        int c4 = f4 & 15;           // d/4
        float4 v = *(const float4*)&Qb[row * HD + c4 * 4];
        Qs[c4 * 4 + 0][row] = v.x;
        Qs[c4 * 4 + 1][row] = v.y;
        Qs[c4 * 4 + 2][row] = v.z;
        Qs[c4 * 4 + 3][row] = v.w;
    }
    if (tid < 64) { m_run[tid] = -1e30f; l_run[tid] = 0.f; }

    float acc[4][4];
#pragma unroll
    for (int i = 0; i < 4; ++i)
#pragma unroll
        for (int j = 0; j < 4; ++j) acc[i][j] = 0.f;

    __syncthreads();

    for (int kt = 0; kt < SEQ / 64; ++kt) {
        // stage K (transposed) and V tiles
#pragma unroll
        for (int l = 0; l < 4; ++l) {
            int f4 = tid + l * 256;
            int row = f4 >> 4;      // k 0..63
            int c4 = f4 & 15;
            float4 kv = *(const float4*)&Kb[(size_t)(kt * 64 + row) * HD + c4 * 4];
            Ks[c4 * 4 + 0][row] = kv.x;
            Ks[c4 * 4 + 1][row] = kv.y;
            Ks[c4 * 4 + 2][row] = kv.z;
            Ks[c4 * 4 + 3][row] = kv.w;
            float4 vv = *(const float4*)&Vb[(size_t)(kt * 64 + row) * HD + c4 * 4];
            *(float4*)&Vs[row][c4 * 4] = vv;
        }
        __syncthreads();

        // scores: thread -> q in [ty*4, +4), k in [tx*4, +4)
        float s[4][4];
#pragma unroll
        for (int i = 0; i < 4; ++i)
#pragma unroll
            for (int j = 0; j < 4; ++j) s[i][j] = 0.f;
#pragma unroll 8
        for (int d = 0; d < 64; ++d) {
            float qv[4], kv[4];
            *(float4*)qv = *(const float4*)&Qs[d][ty * 4];
            *(float4*)kv = *(const float4*)&Ks[d][tx * 4];
#pragma unroll
            for (int i = 0; i < 4; ++i)
#pragma unroll
                for (int j = 0; j < 4; ++j) s[i][j] = fmaf(qv[i], kv[j], s[i][j]);
        }
        // mask, scale, write P^T
#pragma unroll
        for (int i = 0; i < 4; ++i) {
            int ql = ty * 4 + i;
            float4 mv = *(const float4*)&Mb[(size_t)ql * SEQ + kt * 64 + tx * 4];
            const float* mp = &mv.x;
#pragma unroll
            for (int j = 0; j < 4; ++j) {
                Ps[tx * 4 + j][ql] = (mp[j] == 0.f) ? -2e30f : s[i][j] * 0.125f;
            }
        }
        __syncthreads();

        // online softmax: 4 lanes per row (same wave), shfl_xor combine
        {
            int r = tid >> 2;       // 0..63
            int part = tid & 3;     // 16 ks each
            float mold = m_run[r];
            float mx = mold;
#pragma unroll
            for (int t = 0; t < 16; ++t) mx = fmaxf(mx, Ps[part * 16 + t][r]);
            mx = fmaxf(mx, __shfl_xor(mx, 1, 64));
            mx = fmaxf(mx, __shfl_xor(mx, 2, 64));
            float sum = 0.f;
#pragma unroll
            for (int t = 0; t < 16; ++t) {
                int k = part * 16 + t;
                float p = __expf(Ps[k][r] - mx);
                Ps[k][r] = p;
                sum += p;
            }
            sum += __shfl_xor(sum, 1, 64);
            sum += __shfl_xor(sum, 2, 64);
            if (part == 0) {
                m_run[r] = mx;
                float sc = __expf(mold - mx);
                l_run[r] = l_run[r] * sc + sum;
                sc_s[r] = sc;
            }
        }
        __syncthreads();

        // PV: acc[q][e] = acc*sc + sum_k P[k][q] * V[k][e]
        float scq[4];
#pragma unroll
        for (int i = 0; i < 4; ++i) scq[i] = sc_s[ty * 4 + i];
#pragma unroll
        for (int i = 0; i < 4; ++i)
#pragma unroll
            for (int j = 0; j < 4; ++j) acc[i][j] *= scq[i];
#pragma unroll 8
        for (int kk = 0; kk < 64; ++kk) {
            float p[4], vv[4];
#pragma unroll
            for (int i = 0; i < 4; ++i) p[i] = Ps[kk][ty * 4 + i];
            *(float4*)vv = *(const float4*)&Vs[kk][tx * 4];
#pragma unroll
            for (int i = 0; i < 4; ++i)
#pragma unroll
                for (int j = 0; j < 4; ++j) acc[i][j] = fmaf(p[i], vv[j], acc[i][j]);
        }
        __syncthreads();
    }

    // final: divide by l, write O in (b, s, h*HD+e) row-major (= (M, D) for out-proj)
#pragma unroll
    for (int i = 0; i < 4; ++i) {
        float li = 1.f / l_run[ty * 4 + i];
        int srow = qt * 64 + ty * 4 + i;
        float4 v;
        v.x = acc[i][0] * li;
        v.y = acc[i][1] * li;
        v.z = acc[i][2] * li;
        v.w = acc[i][3] * li;
        *(float4*)&O[(size_t)(b * SEQ + srow) * D_EMBED + h * HD + tx * 4] = v;
    }
}

// ---------------------------------------------------------------------------
extern "C" void kernel_launch(void* const* d_in, const int* in_sizes, int n_in,
                              void* d_out, int out_size, void* d_ws, size_t ws_size,
                              hipStream_t stream) {
    const float* x  = (const float*)d_in[0];
    const float* kg = (const float*)d_in[1];
    const float* Wq = (const float*)d_in[2];
    const float* bq = (const float*)d_in[3];
    const float* Wk = (const float*)d_in[4];
    const float* bk = (const float*)d_in[5];
    const float* Wv = (const float*)d_in[6];
    const float* bv = (const float*)d_in[7];
    const float* Wo = (const float*)d_in[8];
    const float* bo = (const float*)d_in[9];
    float* out = (float*)d_out;

    // workspace: Q, K, V in (B,NH,S,HD); O in (B*S, D). 4 x 16.8 MB = 67.1 MB.
    const size_t chunk = (size_t)MTOT * D_EMBED;
    float* qb = (float*)d_ws;
    float* kb = qb + chunk;
    float* vb = kb + chunk;
    float* ob = vb + chunk;

    dim3 gg(D_EMBED / 64, MTOT / 128);  // (16, 32)
    gemm_f32<1><<<gg, 256, 0, stream>>>(x, Wq, bq, qb, MTOT, D_EMBED, D_EMBED);
    gemm_f32<1><<<gg, 256, 0, stream>>>(x, Wk, bk, kb, MTOT, D_EMBED, D_EMBED);
    gemm_f32<1><<<gg, 256, 0, stream>>>(x, Wv, bv, vb, MTOT, D_EMBED, D_EMBED);

    attn_f32<<<dim3(SEQ / 64, BATCH * NH), 256, 0, stream>>>(qb, kb, vb, kg, ob);

    gemm_f32<0><<<gg, 256, 0, stream>>>(ob, Wo, bo, out, MTOT, D_EMBED, D_EMBED);
}

// Round 3
// 335.403 us; speedup vs baseline: 3.5430x; 3.5430x over previous
//
#include <hip/hip_runtime.h>

// KG-constrained attention, bf16 MFMA pipeline.
// B=2, S=2048, D=1024, H=16, HD=64.
// wcvt (W^T->bf16) -> gemm_mfma<fp32A,scatter> x3 (QKV) -> vtr (V->V^T) ->
// attn_mfma (flash, 16x16x32 bf16 MFMA) -> gemm_mfma<bf16A,plain> (out proj, fp32 out)

#define SEQ 2048

typedef __attribute__((ext_vector_type(8))) short short8;   // 8 x bf16 (4 VGPRs) MFMA A/B frag
typedef __attribute__((ext_vector_type(4))) float f32x4;    // MFMA C/D frag

// fp32 -> bf16 (RNE)
__device__ __forceinline__ unsigned short f2b(float f) {
    unsigned u = __builtin_bit_cast(unsigned, f);
    u += 0x7fffu + ((u >> 16) & 1u);
    return (unsigned short)(u >> 16);
}

// ---------------------------------------------------------------------------
// W [1024 k][1024 n] f32  ->  Wt [n][k] bf16   (4 matrices via blockIdx.z)
// ---------------------------------------------------------------------------
__global__ __launch_bounds__(256) void wcvt(const float* __restrict__ W0, const float* __restrict__ W1,
                                            const float* __restrict__ W2, const float* __restrict__ W3,
                                            unsigned short* __restrict__ T0, unsigned short* __restrict__ T1,
                                            unsigned short* __restrict__ T2, unsigned short* __restrict__ T3) {
    const float* W = blockIdx.z == 0 ? W0 : blockIdx.z == 1 ? W1 : blockIdx.z == 2 ? W2 : W3;
    unsigned short* T = blockIdx.z == 0 ? T0 : blockIdx.z == 1 ? T1 : blockIdx.z == 2 ? T2 : T3;
    __shared__ float Ls[64][65];
    const int tid = threadIdx.x;
    const int n0 = blockIdx.x * 64, k0 = blockIdx.y * 64;
#pragma unroll
    for (int i = 0; i < 4; ++i) {
        int q = tid + i * 256; int k = q >> 4, c = q & 15;
        f32x4 v = *(const f32x4*)&W[(size_t)(k0 + k) * 1024 + n0 + c * 4];
        Ls[k][c * 4 + 0] = v[0]; Ls[k][c * 4 + 1] = v[1];
        Ls[k][c * 4 + 2] = v[2]; Ls[k][c * 4 + 3] = v[3];
    }
    __syncthreads();
#pragma unroll
    for (int i = 0; i < 2; ++i) {
        int q = tid + i * 256; int n = q >> 3, c = q & 7;
        short8 ov;
#pragma unroll
        for (int j = 0; j < 8; ++j) ov[j] = (short)f2b(Ls[c * 8 + j][n]);
        *(short8*)&T[(size_t)(n0 + n) * 1024 + k0 + c * 8] = ov;
    }
}

// ---------------------------------------------------------------------------
// V (b,h,s,e) bf16 -> Vt (b,h,e,s) bf16, 64x64 tiles
// ---------------------------------------------------------------------------
__global__ __launch_bounds__(256) void vtr(const unsigned short* __restrict__ V,
                                           unsigned short* __restrict__ Vt) {
    __shared__ __align__(16) unsigned short Ls[64][80];
    const int tid = threadIdx.x;
    const int s0 = blockIdx.x * 64;
    const size_t base = (size_t)blockIdx.y * SEQ * 64;
#pragma unroll
    for (int i = 0; i < 2; ++i) {
        int q = tid + i * 256; int s = q >> 3, c = q & 7;
        *(short8*)&Ls[s][c * 8] = *(const short8*)&V[base + (size_t)(s0 + s) * 64 + c * 8];
    }
    __syncthreads();
#pragma unroll
    for (int i = 0; i < 2; ++i) {
        int q = tid + i * 256; int e = q >> 3, c = q & 7;
        short8 ov;
#pragma unroll
        for (int j = 0; j < 8; ++j) ov[j] = (short)Ls[c * 8 + j][e];
        *(short8*)&Vt[base + (size_t)e * SEQ + s0 + c * 8] = ov;
    }
}

// ---------------------------------------------------------------------------
// GEMM: Y[M=4096][N=1024] = A[4096][1024] @ Wt^T + bias   (Wt is [n][k] bf16)
// 128x128 tile, BK=32, 256 thr (4 waves 2x2), 16x16x32 bf16 MFMA.
// A_BF16: A is bf16 (else fp32, converted in staging regs).
// SCATTER: write bf16 to (b,h,s,e); else fp32 row-major.
// XOR-swizzled LDS (byte ^= (row&7)<<4 within 64B rows) -> ~2-way max conflicts.
// Reg-prefetch of next K-step overlaps global latency with MFMA.
// ---------------------------------------------------------------------------
template <int A_BF16, int SCATTER>
__global__ __launch_bounds__(256) void gemm_mfma(const void* __restrict__ Ap,
                                                 const unsigned short* __restrict__ Bt,
                                                 const float* __restrict__ bias,
                                                 void* __restrict__ Yp) {
    __shared__ __align__(16) char AsB[8192];
    __shared__ __align__(16) char BsB[8192];
    const int tid = threadIdx.x;
    const int w = tid >> 6, l = tid & 63, lo = l & 15, hi = l >> 4;
    const int m0 = blockIdx.y * 128, n0 = blockIdx.x * 128;
    const int wm = (w & 1) * 64, wn = (w >> 1) * 64;
    const float* Af = (const float*)Ap;
    const unsigned short* Ab = (const unsigned short*)Ap;

    f32x4 acc[4][4];
#pragma unroll
    for (int i = 0; i < 4; ++i)
#pragma unroll
        for (int j = 0; j < 4; ++j) acc[i][j] = f32x4{0.f, 0.f, 0.f, 0.f};

    const int cm = tid >> 2, cc = tid & 3;   // chunk (row, 16B-col); rows cm and cm+64
    f32x4 fa[2][2]; short8 fa8[2]; short8 fb[2];

    auto FETCH = [&](int kk) {
#pragma unroll
        for (int i = 0; i < 2; ++i) {
            int m = cm + 64 * i;
            if (A_BF16) {
                fa8[i] = *(const short8*)&Ab[(size_t)(m0 + m) * 1024 + kk + cc * 8];
            } else {
                fa[i][0] = *(const f32x4*)&Af[(size_t)(m0 + m) * 1024 + kk + cc * 8];
                fa[i][1] = *(const f32x4*)&Af[(size_t)(m0 + m) * 1024 + kk + cc * 8 + 4];
            }
            fb[i] = *(const short8*)&Bt[(size_t)(n0 + m) * 1024 + kk + cc * 8];
        }
    };

    FETCH(0);
    for (int k0 = 0; k0 < 1024; k0 += 32) {
#pragma unroll
        for (int i = 0; i < 2; ++i) {
            int m = cm + 64 * i;
            int dst = (m * 64 + cc * 16) ^ ((m & 7) << 4);
            short8 av;
            if (A_BF16) av = fa8[i];
            else {
#pragma unroll
                for (int j = 0; j < 4; ++j) {
                    av[j] = (short)f2b(fa[i][0][j]);
                    av[4 + j] = (short)f2b(fa[i][1][j]);
                }
            }
            *(short8*)(AsB + dst) = av;
            *(short8*)(BsB + dst) = fb[i];
        }
        __syncthreads();
        if (k0 + 32 < 1024) FETCH(k0 + 32);

        short8 af_[4], bf_[4];
#pragma unroll
        for (int t = 0; t < 4; ++t) {
            int r = wm + t * 16 + lo;
            af_[t] = *(const short8*)(AsB + ((r * 64 + hi * 16) ^ ((r & 7) << 4)));
            int rn = wn + t * 16 + lo;
            bf_[t] = *(const short8*)(BsB + ((rn * 64 + hi * 16) ^ ((rn & 7) << 4)));
        }
#pragma unroll
        for (int mt = 0; mt < 4; ++mt)
#pragma unroll
            for (int nt = 0; nt < 4; ++nt)
                acc[mt][nt] = __builtin_amdgcn_mfma_f32_16x16x32_bf16(af_[mt], bf_[nt], acc[mt][nt], 0, 0, 0);
        __syncthreads();
    }

    float bv[4];
#pragma unroll
    for (int nt = 0; nt < 4; ++nt) bv[nt] = bias[n0 + wn + nt * 16 + lo];
#pragma unroll
    for (int mt = 0; mt < 4; ++mt)
#pragma unroll
        for (int nt = 0; nt < 4; ++nt)
#pragma unroll
            for (int r = 0; r < 4; ++r) {
                float v = acc[mt][nt][r] + bv[nt];
                int m = m0 + wm + mt * 16 + hi * 4 + r;   // D frag: row = hi*4+reg
                int n = n0 + wn + nt * 16 + lo;           //         col = lane&15
                if (SCATTER) {
                    int b = m >> 11, s = m & 2047, hh = n >> 6, e = n & 63;
                    ((unsigned short*)Yp)[(size_t)((b * 16 + hh) * SEQ + s) * 64 + e] = f2b(v);
                } else {
                    ((float*)Yp)[(size_t)m * 1024 + n] = v;
                }
            }
}

// ---------------------------------------------------------------------------
// Flash attention, bf16 MFMA. Grid (SEQ/64, B*H), 256 thr = 4 waves.
// Wave w owns 16 q rows. Swapped QK^T: St = mfma(K, Q) -> St col = q = lane&15,
// so softmax stats are lane-local. P transposed to PV-A layout via per-wave
// 2KB swizzled LDS round-trip. V consumed from Vt (b,h,e,s).
// ---------------------------------------------------------------------------
__global__ __launch_bounds__(256) void attn_mfma(const unsigned short* __restrict__ Qg,
                                                 const unsigned short* __restrict__ Kg,
                                                 const unsigned short* __restrict__ Vtg,
                                                 const float* __restrict__ mask,
                                                 unsigned short* __restrict__ Og) {
    __shared__ __align__(16) char KsB[8192];
    __shared__ __align__(16) char VsB[8192];
    __shared__ __align__(16) char PsB[8192];
    const int tid = threadIdx.x;
    const int w = tid >> 6, l = tid & 63, lo = l & 15, hi = l >> 4;
    const int qt = blockIdx.x, bh = blockIdx.y, b = bh >> 4, h = bh & 15;

    const unsigned short* Qp = Qg + ((size_t)bh * SEQ + qt * 64 + w * 16 + lo) * 64;
    const short8 qf0 = *(const short8*)(Qp + hi * 8);        // hd 0..31 chunk
    const short8 qf1 = *(const short8*)(Qp + 32 + hi * 8);   // hd 32..63 chunk
    const unsigned short* Kb = Kg + (size_t)bh * SEQ * 64;
    const unsigned short* Vb = Vtg + (size_t)bh * 64 * SEQ;
    const float* mrow = mask + (size_t)b * SEQ * SEQ + (size_t)(qt * 64 + w * 16 + lo) * SEQ;
    char* PsW = PsB + w * 2048;

    float m_run = -1e30f, l_run = 0.f;
    f32x4 acc[4];
#pragma unroll
    for (int nt = 0; nt < 4; ++nt) acc[nt] = f32x4{0.f, 0.f, 0.f, 0.f};

    const int sk = tid >> 3, scol = tid & 7;   // staging: rows sk, sk+32; 16B col scol
    short8 pk[2], pv[2];
    auto FETCH = [&](int kv) {
#pragma unroll
        for (int i = 0; i < 2; ++i) {
            int row = sk + 32 * i;
            pk[i] = *(const short8*)&Kb[(size_t)(kv * 64 + row) * 64 + scol * 8];
            pv[i] = *(const short8*)&Vb[(size_t)row * SEQ + kv * 64 + scol * 8];
        }
    };

    FETCH(0);
    for (int kv = 0; kv < 32; ++kv) {
#pragma unroll
        for (int i = 0; i < 2; ++i) {
            int row = sk + 32 * i;
            int dst = (row * 128 + scol * 16) ^ ((row & 7) << 4);
            *(short8*)(KsB + dst) = pk[i];
            *(short8*)(VsB + dst) = pv[i];
        }
        __syncthreads();
        if (kv + 1 < 32) FETCH(kv + 1);

        f32x4 mv[4];
#pragma unroll
        for (int kt = 0; kt < 4; ++kt)
            mv[kt] = *(const f32x4*)&mrow[kv * 64 + kt * 16 + hi * 4];

        // St[key][q] = K . Q^T : A frag = K rows, B frag = Q rows
        f32x4 st[4];
#pragma unroll
        for (int kt = 0; kt < 4; ++kt) {
            int r = kt * 16 + lo;
            short8 kf0 = *(const short8*)(KsB + ((r * 128 + hi * 16) ^ ((lo & 7) << 4)));
            short8 kf1 = *(const short8*)(KsB + ((r * 128 + 64 + hi * 16) ^ ((lo & 7) << 4)));
            f32x4 z = {0.f, 0.f, 0.f, 0.f};
            z = __builtin_amdgcn_mfma_f32_16x16x32_bf16(kf0, qf0, z, 0, 0, 0);
            st[kt] = __builtin_amdgcn_mfma_f32_16x16x32_bf16(kf1, qf1, z, 0, 0, 0);
        }

        // mask + scale; lane holds 16 scores for q = lo: keys kt*16 + hi*4 + r
        const float mold = m_run;
        float mx = mold;
#pragma unroll
        for (int kt = 0; kt < 4; ++kt)
#pragma unroll
            for (int r = 0; r < 4; ++r) {
                float sv = (mv[kt][r] == 0.f) ? -2e30f : st[kt][r] * 0.125f;
                st[kt][r] = sv;
                mx = fmaxf(mx, sv);
            }
        mx = fmaxf(mx, __shfl_xor(mx, 16, 64));
        mx = fmaxf(mx, __shfl_xor(mx, 32, 64));

        float sum = 0.f;
        unsigned wpk[4][2];
#pragma unroll
        for (int kt = 0; kt < 4; ++kt) {
            float p0 = __expf(st[kt][0] - mx), p1 = __expf(st[kt][1] - mx);
            float p2 = __expf(st[kt][2] - mx), p3 = __expf(st[kt][3] - mx);
            sum += (p0 + p1) + (p2 + p3);
            wpk[kt][0] = (unsigned)f2b(p0) | ((unsigned)f2b(p1) << 16);
            wpk[kt][1] = (unsigned)f2b(p2) | ((unsigned)f2b(p3) << 16);
        }
        sum += __shfl_xor(sum, 16, 64);
        sum += __shfl_xor(sum, 32, 64);
        const float scf = __expf(mold - mx);
        l_run = l_run * scf + sum;
        m_run = mx;

        // write P^(q=lo) rows to per-wave swizzled LDS, read back as PV A-frags
#pragma unroll
        for (int kt = 0; kt < 4; ++kt) {
            int d0 = (lo * 128 + kt * 32 + hi * 8) ^ ((lo & 7) << 4);
            *(unsigned*)(PsW + d0) = wpk[kt][0];
            *(unsigned*)(PsW + d0 + 4) = wpk[kt][1];
        }

        // rescale O by exp(m_old - m_new), per q' = hi*4 + r (D-frag rows)
        float scr[4];
#pragma unroll
        for (int r = 0; r < 4; ++r) scr[r] = __shfl(scf, (hi << 2) + r, 64);
#pragma unroll
        for (int nt = 0; nt < 4; ++nt)
#pragma unroll
            for (int r = 0; r < 4; ++r) acc[nt][r] *= scr[r];

        short8 pa0 = *(const short8*)(PsW + ((lo * 128 + hi * 16) ^ ((lo & 7) << 4)));
        short8 pa1 = *(const short8*)(PsW + ((lo * 128 + 64 + hi * 16) ^ ((lo & 7) << 4)));
#pragma unroll
        for (int nt = 0; nt < 4; ++nt) {
            int r = nt * 16 + lo;
            short8 v0 = *(const short8*)(VsB + ((r * 128 + hi * 16) ^ ((lo & 7) << 4)));
            short8 v1 = *(const short8*)(VsB + ((r * 128 + 64 + hi * 16) ^ ((lo & 7) << 4)));
            acc[nt] = __builtin_amdgcn_mfma_f32_16x16x32_bf16(pa0, v0, acc[nt], 0, 0, 0);
            acc[nt] = __builtin_amdgcn_mfma_f32_16x16x32_bf16(pa1, v1, acc[nt], 0, 0, 0);
        }
        __syncthreads();
    }

    float lr[4];
#pragma unroll
    for (int r = 0; r < 4; ++r) lr[r] = 1.f / __shfl(l_run, (hi << 2) + r, 64);
#pragma unroll
    for (int nt = 0; nt < 4; ++nt)
#pragma unroll
        for (int r = 0; r < 4; ++r) {
            int qg2 = qt * 64 + w * 16 + hi * 4 + r;
            Og[(size_t)(b * SEQ + qg2) * 1024 + h * 64 + nt * 16 + lo] = f2b(acc[nt][r] * lr[r]);
        }
}

// ---------------------------------------------------------------------------
extern "C" void kernel_launch(void* const* d_in, const int* in_sizes, int n_in,
                              void* d_out, int out_size, void* d_ws, size_t ws_size,
                              hipStream_t stream) {
    const float* x  = (const float*)d_in[0];
    const float* kg = (const float*)d_in[1];
    const float* Wq = (const float*)d_in[2];
    const float* bq = (const float*)d_in[3];
    const float* Wk = (const float*)d_in[4];
    const float* bk = (const float*)d_in[5];
    const float* Wv = (const float*)d_in[6];
    const float* bv = (const float*)d_in[7];
    const float* Wo = (const float*)d_in[8];
    const float* bo = (const float*)d_in[9];

    unsigned short* ws = (unsigned short*)d_ws;
    const size_t WSZ = 1024 * 1024;        // elems per Wt
    const size_t CH  = (size_t)4096 * 1024; // elems per activation
    unsigned short* wtq = ws;
    unsigned short* wtk = ws + WSZ;
    unsigned short* wtv = ws + 2 * WSZ;
    unsigned short* wto = ws + 3 * WSZ;
    unsigned short* qb  = ws + 4 * WSZ;
    unsigned short* kb  = qb + CH;
    unsigned short* vb  = kb + CH;
    unsigned short* vt  = vb + CH;
    unsigned short* ob  = vt + CH;

    wcvt<<<dim3(16, 16, 4), 256, 0, stream>>>(Wq, Wk, Wv, Wo, wtq, wtk, wtv, wto);

    dim3 gg(8, 32);
    gemm_mfma<0, 1><<<gg, 256, 0, stream>>>(x, wtq, bq, qb);
    gemm_mfma<0, 1><<<gg, 256, 0, stream>>>(x, wtk, bk, kb);
    gemm_mfma<0, 1><<<gg, 256, 0, stream>>>(x, wtv, bv, vb);

    vtr<<<dim3(32, 32), 256, 0, stream>>>(vb, vt);

    attn_mfma<<<dim3(32, 32), 256, 0, stream>>>(qb, kb, vt, kg, ob);

    gemm_mfma<1, 0><<<gg, 256, 0, stream>>>(ob, wto, bo, d_out);
}

// Round 9
// 275.229 us; speedup vs baseline: 4.3177x; 1.2186x over previous
//
#include <hip/hip_runtime.h>
#include <hip/hip_bf16.h>

// KG-constrained attention, bf16 MFMA pipeline, round 6 (compile-fixed r4).
// B=2, S=2048, D=1024, H=16, HD=64.
// xcvt (x->bf16) + wcvt (W^T->bf16, Q-branch pre-scaled by 0.125*log2e) ->
// fused QKV gemm (N=3072, scatter) -> vtr -> attn (exp2-domain softmax,
// defer-max, hw cvt_pk, setprio) -> out-proj gemm.

#define SEQ 2048
#define SCEXP 0.18033688011112043f   // 1/sqrt(64) * log2(e)

typedef __attribute__((ext_vector_type(8))) short short8;   // 8 x bf16 MFMA A/B frag
typedef __attribute__((ext_vector_type(4))) float f32x4;    // MFMA C/D frag

union S8U {
    short8 s;
    unsigned u[4];
};

// fp32 -> bf16 (RNE) — epilogue-class use only
__device__ __forceinline__ unsigned short f2b(float f) {
    unsigned u = __builtin_bit_cast(unsigned, f);
    u += 0x7fffu + ((u >> 16) & 1u);
    return (unsigned short)(u >> 16);
}

// two fp32 -> packed 2x bf16 (hardware v_cvt_pk_bf16_f32)
__device__ __forceinline__ unsigned pk2(float a, float b) {
    __hip_bfloat162 h = __float22bfloat162_rn(float2{a, b});
    unsigned r;
    __builtin_memcpy(&r, &h, 4);
    return r;
}

// ---------------------------------------------------------------------------
// x [4096][1024] f32 -> bf16 same layout
// ---------------------------------------------------------------------------
__global__ __launch_bounds__(256) void xcvt(const float* __restrict__ X,
                                            unsigned short* __restrict__ Xb) {
    const size_t base = ((size_t)blockIdx.x * 256 + threadIdx.x) * 8;
    f32x4 v0 = *(const f32x4*)&X[base];
    f32x4 v1 = *(const f32x4*)&X[base + 4];
    S8U o;
    o.u[0] = pk2(v0[0], v0[1]);
    o.u[1] = pk2(v0[2], v0[3]);
    o.u[2] = pk2(v1[0], v1[1]);
    o.u[3] = pk2(v1[2], v1[3]);
    *(short8*)&Xb[base] = o.s;
}

// ---------------------------------------------------------------------------
// W [1024 k][1024 n] f32 -> Wt [n][k] bf16 (4 matrices via blockIdx.z)
// z==0 (Wq) scaled by SCEXP so QK^T scores arrive in exp2 domain.
// ---------------------------------------------------------------------------
__global__ __launch_bounds__(256) void wcvt(const float* __restrict__ W0, const float* __restrict__ W1,
                                            const float* __restrict__ W2, const float* __restrict__ W3,
                                            unsigned short* __restrict__ T0, unsigned short* __restrict__ T1,
                                            unsigned short* __restrict__ T2, unsigned short* __restrict__ T3) {
    const float* W = blockIdx.z == 0 ? W0 : blockIdx.z == 1 ? W1 : blockIdx.z == 2 ? W2 : W3;
    unsigned short* T = blockIdx.z == 0 ? T0 : blockIdx.z == 1 ? T1 : blockIdx.z == 2 ? T2 : T3;
    const float sc = (blockIdx.z == 0) ? SCEXP : 1.f;
    __shared__ float Ls[64][65];
    const int tid = threadIdx.x;
    const int n0 = blockIdx.x * 64, k0 = blockIdx.y * 64;
#pragma unroll
    for (int i = 0; i < 4; ++i) {
        int q = tid + i * 256; int k = q >> 4, c = q & 15;
        f32x4 v = *(const f32x4*)&W[(size_t)(k0 + k) * 1024 + n0 + c * 4];
        Ls[k][c * 4 + 0] = v[0]; Ls[k][c * 4 + 1] = v[1];
        Ls[k][c * 4 + 2] = v[2]; Ls[k][c * 4 + 3] = v[3];
    }
    __syncthreads();
#pragma unroll
    for (int i = 0; i < 2; ++i) {
        int q = tid + i * 256; int n = q >> 3, c = q & 7;
        short8 ov;
#pragma unroll
        for (int j = 0; j < 8; ++j) ov[j] = (short)f2b(Ls[c * 8 + j][n] * sc);
        *(short8*)&T[(size_t)(n0 + n) * 1024 + k0 + c * 8] = ov;
    }
}

// ---------------------------------------------------------------------------
// V (b,h,s,e) bf16 -> Vt (b,h,e,s) bf16, 64x64 tiles
// ---------------------------------------------------------------------------
__global__ __launch_bounds__(256) void vtr(const unsigned short* __restrict__ V,
                                           unsigned short* __restrict__ Vt) {
    __shared__ __align__(16) unsigned short Ls[64][80];
    const int tid = threadIdx.x;
    const int s0 = blockIdx.x * 64;
    const size_t base = (size_t)blockIdx.y * SEQ * 64;
#pragma unroll
    for (int i = 0; i < 2; ++i) {
        int q = tid + i * 256; int s = q >> 3, c = q & 7;
        *(short8*)&Ls[s][c * 8] = *(const short8*)&V[base + (size_t)(s0 + s) * 64 + c * 8];
    }
    __syncthreads();
#pragma unroll
    for (int i = 0; i < 2; ++i) {
        int q = tid + i * 256; int e = q >> 3, c = q & 7;
        short8 ov;
#pragma unroll
        for (int j = 0; j < 8; ++j) ov[j] = (short)Ls[c * 8 + j][e];
        *(short8*)&Vt[base + (size_t)e * SEQ + s0 + c * 8] = ov;
    }
}

// ---------------------------------------------------------------------------
// GEMM: Y = A[4096][1024] @ Wt^T + bias. 128x128 tile, BK=32, 4 waves.
// MODE 0: fp32 row-major out (N=1024), bias b0.
// MODE 1: fused QKV (N=3072): block-uniform which=n0>>10 selects bias b0/b1/b2
//         (b0 scaled by SCEXP) and scatter chunk; bf16 scatter to (b,h,s,e).
// A always bf16. XOR-swizzled LDS; reg-prefetch of next K-step.
// ---------------------------------------------------------------------------
#define CHE ((size_t)4096 * 1024)   // elems per activation chunk

template <int MODE>
__global__ __launch_bounds__(256) void gemm_mfma(const unsigned short* __restrict__ Ab,
                                                 const unsigned short* __restrict__ Bt,
                                                 const float* __restrict__ b0,
                                                 const float* __restrict__ b1,
                                                 const float* __restrict__ b2,
                                                 void* __restrict__ Yp) {
    __shared__ __align__(16) char AsB[8192];
    __shared__ __align__(16) char BsB[8192];
    const int tid = threadIdx.x;
    const int w = tid >> 6, l = tid & 63, lo = l & 15, hi = l >> 4;
    const int m0 = blockIdx.y * 128, n0 = blockIdx.x * 128;
    const int wm = (w & 1) * 64, wn = (w >> 1) * 64;
    const int which = (MODE == 1) ? (n0 >> 10) : 0;
    const float* biasp = which == 0 ? b0 : which == 1 ? b1 : b2;
    const float bsc = (MODE == 1 && which == 0) ? SCEXP : 1.f;

    f32x4 acc[4][4];
#pragma unroll
    for (int i = 0; i < 4; ++i)
#pragma unroll
        for (int j = 0; j < 4; ++j) acc[i][j] = f32x4{0.f, 0.f, 0.f, 0.f};

    const int cm = tid >> 2, cc = tid & 3;
    short8 fa8[2], fb[2];
    auto FETCH = [&](int kk) {
#pragma unroll
        for (int i = 0; i < 2; ++i) {
            int m = cm + 64 * i;
            fa8[i] = *(const short8*)&Ab[(size_t)(m0 + m) * 1024 + kk + cc * 8];
            fb[i] = *(const short8*)&Bt[(size_t)(n0 + m) * 1024 + kk + cc * 8];
        }
    };

    FETCH(0);
    for (int k0 = 0; k0 < 1024; k0 += 32) {
#pragma unroll
        for (int i = 0; i < 2; ++i) {
            int m = cm + 64 * i;
            int dst = (m * 64 + cc * 16) ^ ((m & 7) << 4);
            *(short8*)(AsB + dst) = fa8[i];
            *(short8*)(BsB + dst) = fb[i];
        }
        __syncthreads();
        if (k0 + 32 < 1024) FETCH(k0 + 32);

        short8 af_[4], bf_[4];
#pragma unroll
        for (int t = 0; t < 4; ++t) {
            int r = wm + t * 16 + lo;
            af_[t] = *(const short8*)(AsB + ((r * 64 + hi * 16) ^ ((r & 7) << 4)));
            int rn = wn + t * 16 + lo;
            bf_[t] = *(const short8*)(BsB + ((rn * 64 + hi * 16) ^ ((rn & 7) << 4)));
        }
        __builtin_amdgcn_s_setprio(1);
#pragma unroll
        for (int mt = 0; mt < 4; ++mt)
#pragma unroll
            for (int nt = 0; nt < 4; ++nt)
                acc[mt][nt] = __builtin_amdgcn_mfma_f32_16x16x32_bf16(af_[mt], bf_[nt], acc[mt][nt], 0, 0, 0);
        __builtin_amdgcn_s_setprio(0);
        __syncthreads();
    }

    float bv[4];
#pragma unroll
    for (int nt = 0; nt < 4; ++nt)
        bv[nt] = biasp[(n0 & 1023) + wn + nt * 16 + lo] * bsc;
#pragma unroll
    for (int mt = 0; mt < 4; ++mt)
#pragma unroll
        for (int nt = 0; nt < 4; ++nt)
#pragma unroll
            for (int r = 0; r < 4; ++r) {
                float v = acc[mt][nt][r] + bv[nt];
                int m = m0 + wm + mt * 16 + hi * 4 + r;
                int nloc = (n0 & 1023) + wn + nt * 16 + lo;
                if (MODE == 1) {
                    int b = m >> 11, s = m & 2047, hh = nloc >> 6, e = nloc & 63;
                    ((unsigned short*)Yp)[(size_t)which * CHE + (size_t)((b * 16 + hh) * SEQ + s) * 64 + e] = f2b(v);
                } else {
                    ((float*)Yp)[(size_t)m * 1024 + nloc] = v;
                }
            }
}

// ---------------------------------------------------------------------------
// Flash attention, bf16 MFMA, exp2-domain softmax (Q pre-scaled by SCEXP).
// Grid (SEQ/64, B*H), 256 thr = 4 waves, 16 q rows/wave.
// Swapped QK^T -> stats lane-local. Defer-max (THR=8). Masked = -2e30
// (< m_init -1e30, so fully-masked tiles give exact p=0, never poison m_run).
// ---------------------------------------------------------------------------
__global__ __launch_bounds__(256) void attn_mfma(const unsigned short* __restrict__ Qg,
                                                 const unsigned short* __restrict__ Kg,
                                                 const unsigned short* __restrict__ Vtg,
                                                 const float* __restrict__ mask,
                                                 unsigned short* __restrict__ Og) {
    __shared__ __align__(16) char KsB[8192];
    __shared__ __align__(16) char VsB[8192];
    __shared__ __align__(16) char PsB[8192];
    const int tid = threadIdx.x;
    const int w = tid >> 6, l = tid & 63, lo = l & 15, hi = l >> 4;
    const int qt = blockIdx.x, bh = blockIdx.y, b = bh >> 4, h = bh & 15;

    const unsigned short* Qp = Qg + ((size_t)bh * SEQ + qt * 64 + w * 16 + lo) * 64;
    const short8 qf0 = *(const short8*)(Qp + hi * 8);
    const short8 qf1 = *(const short8*)(Qp + 32 + hi * 8);
    const unsigned short* Kb = Kg + (size_t)bh * SEQ * 64;
    const unsigned short* Vb = Vtg + (size_t)bh * 64 * SEQ;
    const float* mrow = mask + (size_t)b * SEQ * SEQ + (size_t)(qt * 64 + w * 16 + lo) * SEQ;
    char* PsW = PsB + w * 2048;

    float m_run = -1e30f, l_run = 0.f;
    const float MASKED = -2e30f;
    f32x4 acc[4];
#pragma unroll
    for (int nt = 0; nt < 4; ++nt) acc[nt] = f32x4{0.f, 0.f, 0.f, 0.f};

    const int sk = tid >> 3, scol = tid & 7;
    short8 pk[2], pv[2];
    f32x4 pm[4];
    auto FETCH = [&](int kv) {
#pragma unroll
        for (int i = 0; i < 2; ++i) {
            int row = sk + 32 * i;
            pk[i] = *(const short8*)&Kb[(size_t)(kv * 64 + row) * 64 + scol * 8];
            pv[i] = *(const short8*)&Vb[(size_t)row * SEQ + kv * 64 + scol * 8];
        }
#pragma unroll
        for (int kt = 0; kt < 4; ++kt)
            pm[kt] = *(const f32x4*)&mrow[kv * 64 + kt * 16 + hi * 4];
    };

    FETCH(0);
    for (int kv = 0; kv < 32; ++kv) {
#pragma unroll
        for (int i = 0; i < 2; ++i) {
            int row = sk + 32 * i;
            int dst = (row * 128 + scol * 16) ^ ((row & 7) << 4);
            *(short8*)(KsB + dst) = pk[i];
            *(short8*)(VsB + dst) = pv[i];
        }
        f32x4 mv[4];
#pragma unroll
        for (int kt = 0; kt < 4; ++kt) mv[kt] = pm[kt];
        __syncthreads();
        if (kv + 1 < 32) FETCH(kv + 1);

        // St[key][q] = K . Q^T (already exp2-scaled via Q)
        f32x4 st[4];
        __builtin_amdgcn_s_setprio(1);
#pragma unroll
        for (int kt = 0; kt < 4; ++kt) {
            int r = kt * 16 + lo;
            short8 kf0 = *(const short8*)(KsB + ((r * 128 + hi * 16) ^ ((lo & 7) << 4)));
            short8 kf1 = *(const short8*)(KsB + ((r * 128 + 64 + hi * 16) ^ ((lo & 7) << 4)));
            f32x4 z = {0.f, 0.f, 0.f, 0.f};
            z = __builtin_amdgcn_mfma_f32_16x16x32_bf16(kf0, qf0, z, 0, 0, 0);
            st[kt] = __builtin_amdgcn_mfma_f32_16x16x32_bf16(kf1, qf1, z, 0, 0, 0);
        }
        __builtin_amdgcn_s_setprio(0);

        // mask select; local max
        float pmax = MASKED;
#pragma unroll
        for (int kt = 0; kt < 4; ++kt)
#pragma unroll
            for (int r = 0; r < 4; ++r) {
                float sv = (mv[kt][r] == 0.f) ? MASKED : st[kt][r];
                st[kt][r] = sv;
                pmax = fmaxf(pmax, sv);
            }
        pmax = fmaxf(pmax, __shfl_xor(pmax, 16, 64));
        pmax = fmaxf(pmax, __shfl_xor(pmax, 32, 64));

        // defer-max: only rescale when a lane's tile-max exceeds m_run + 8
        if (!__all(pmax <= m_run + 8.f)) {
            float mnew = fmaxf(m_run, pmax);
            float scf = __builtin_amdgcn_exp2f(m_run - mnew);
            l_run *= scf;
            float scr[4];
#pragma unroll
            for (int r = 0; r < 4; ++r) scr[r] = __shfl(scf, (hi << 2) + r, 64);
#pragma unroll
            for (int nt = 0; nt < 4; ++nt)
#pragma unroll
                for (int r = 0; r < 4; ++r) acc[nt][r] *= scr[r];
            m_run = mnew;
        }

        // p = exp2(sv - m), sum, pack (hw cvt_pk)
        float sum = 0.f;
        unsigned wpk[4][2];
#pragma unroll
        for (int kt = 0; kt < 4; ++kt) {
            float p0 = __builtin_amdgcn_exp2f(st[kt][0] - m_run);
            float p1 = __builtin_amdgcn_exp2f(st[kt][1] - m_run);
            float p2 = __builtin_amdgcn_exp2f(st[kt][2] - m_run);
            float p3 = __builtin_amdgcn_exp2f(st[kt][3] - m_run);
            sum += (p0 + p1) + (p2 + p3);
            wpk[kt][0] = pk2(p0, p1);
            wpk[kt][1] = pk2(p2, p3);
        }
        sum += __shfl_xor(sum, 16, 64);
        sum += __shfl_xor(sum, 32, 64);
        l_run += sum;

        // P rows -> per-wave swizzled LDS -> PV A-frags
#pragma unroll
        for (int kt = 0; kt < 4; ++kt) {
            int d0 = (lo * 128 + kt * 32 + hi * 8) ^ ((lo & 7) << 4);
            *(unsigned*)(PsW + d0) = wpk[kt][0];
            *(unsigned*)(PsW + d0 + 4) = wpk[kt][1];
        }
        short8 pa0 = *(const short8*)(PsW + ((lo * 128 + hi * 16) ^ ((lo & 7) << 4)));
        short8 pa1 = *(const short8*)(PsW + ((lo * 128 + 64 + hi * 16) ^ ((lo & 7) << 4)));
        __builtin_amdgcn_s_setprio(1);
#pragma unroll
        for (int nt = 0; nt < 4; ++nt) {
            int r = nt * 16 + lo;
            short8 v0 = *(const short8*)(VsB + ((r * 128 + hi * 16) ^ ((lo & 7) << 4)));
            short8 v1 = *(const short8*)(VsB + ((r * 128 + 64 + hi * 16) ^ ((lo & 7) << 4)));
            acc[nt] = __builtin_amdgcn_mfma_f32_16x16x32_bf16(pa0, v0, acc[nt], 0, 0, 0);
            acc[nt] = __builtin_amdgcn_mfma_f32_16x16x32_bf16(pa1, v1, acc[nt], 0, 0, 0);
        }
        __builtin_amdgcn_s_setprio(0);
        __syncthreads();
    }

    float lr[4];
#pragma unroll
    for (int r = 0; r < 4; ++r) lr[r] = 1.f / __shfl(l_run, (hi << 2) + r, 64);
#pragma unroll
    for (int nt = 0; nt < 4; ++nt)
#pragma unroll
        for (int r = 0; r < 4; ++r) {
            int qg2 = qt * 64 + w * 16 + hi * 4 + r;
            Og[(size_t)(b * SEQ + qg2) * 1024 + h * 64 + nt * 16 + lo] = f2b(acc[nt][r] * lr[r]);
        }
}

// ---------------------------------------------------------------------------
extern "C" void kernel_launch(void* const* d_in, const int* in_sizes, int n_in,
                              void* d_out, int out_size, void* d_ws, size_t ws_size,
                              hipStream_t stream) {
    const float* x  = (const float*)d_in[0];
    const float* kg = (const float*)d_in[1];
    const float* Wq = (const float*)d_in[2];
    const float* bq = (const float*)d_in[3];
    const float* Wk = (const float*)d_in[4];
    const float* bk = (const float*)d_in[5];
    const float* Wv = (const float*)d_in[6];
    const float* bv = (const float*)d_in[7];
    const float* Wo = (const float*)d_in[8];
    const float* bo = (const float*)d_in[9];

    unsigned short* ws = (unsigned short*)d_ws;
    const size_t WSZ = 1024 * 1024;
    unsigned short* wtq = ws;                 // [3072][1024] concat q,k,v
    unsigned short* wtk = ws + WSZ;
    unsigned short* wtv = ws + 2 * WSZ;
    unsigned short* wto = ws + 3 * WSZ;
    unsigned short* xb  = ws + 4 * WSZ;       // x bf16
    unsigned short* qb  = ws + 8 * WSZ;       // q,k,v chunks (scatter target base)
    unsigned short* kb  = qb + CHE;
    unsigned short* vb  = kb + CHE;
    unsigned short* vt  = vb + CHE;
    unsigned short* ob  = vt + CHE;

    xcvt<<<2048, 256, 0, stream>>>(x, xb);
    wcvt<<<dim3(16, 16, 4), 256, 0, stream>>>(Wq, Wk, Wv, Wo, wtq, wtk, wtv, wto);

    gemm_mfma<1><<<dim3(24, 32), 256, 0, stream>>>(xb, wtq, bq, bk, bv, qb);

    vtr<<<dim3(32, 32), 256, 0, stream>>>(vb, vt);

    attn_mfma<<<dim3(32, 32), 256, 0, stream>>>(qb, kb, vt, kg, ob);

    gemm_mfma<0><<<dim3(8, 32), 256, 0, stream>>>(ob, wto, bo, bo, bo, d_out);
}

// Round 12
// 244.476 us; speedup vs baseline: 4.8608x; 1.1258x over previous
//
#include <hip/hip_runtime.h>
#include <hip/hip_bf16.h>

// KG-constrained attention, bf16 MFMA pipeline, round 10 (resubmit).
// B=2, S=2048, D=1024, H=16, HD=64.
// Change vs r9: attn_mfma restructured to 8-wave / QBLK=128 / double-buffered
// K,V LDS with ONE barrier per K-tile (was 4-wave / QBLK=64 / 2 barriers).
// Theory: attn was latency/barrier-bound (Occ 23%, MfmaUtil 12%), not VALU-bound.

#define SEQ 2048
#define SCEXP 0.18033688011112043f   // 1/sqrt(64) * log2(e)

typedef __attribute__((ext_vector_type(8))) short short8;   // 8 x bf16 MFMA A/B frag
typedef __attribute__((ext_vector_type(4))) float f32x4;    // MFMA C/D frag

union S8U {
    short8 s;
    unsigned u[4];
};

// fp32 -> bf16 (RNE) — epilogue-class use only
__device__ __forceinline__ unsigned short f2b(float f) {
    unsigned u = __builtin_bit_cast(unsigned, f);
    u += 0x7fffu + ((u >> 16) & 1u);
    return (unsigned short)(u >> 16);
}

// two fp32 -> packed 2x bf16 (hardware v_cvt_pk_bf16_f32)
__device__ __forceinline__ unsigned pk2(float a, float b) {
    __hip_bfloat162 h = __float22bfloat162_rn(float2{a, b});
    unsigned r;
    __builtin_memcpy(&r, &h, 4);
    return r;
}

// ---------------------------------------------------------------------------
// x [4096][1024] f32 -> bf16 same layout
// ---------------------------------------------------------------------------
__global__ __launch_bounds__(256) void xcvt(const float* __restrict__ X,
                                            unsigned short* __restrict__ Xb) {
    const size_t base = ((size_t)blockIdx.x * 256 + threadIdx.x) * 8;
    f32x4 v0 = *(const f32x4*)&X[base];
    f32x4 v1 = *(const f32x4*)&X[base + 4];
    S8U o;
    o.u[0] = pk2(v0[0], v0[1]);
    o.u[1] = pk2(v0[2], v0[3]);
    o.u[2] = pk2(v1[0], v1[1]);
    o.u[3] = pk2(v1[2], v1[3]);
    *(short8*)&Xb[base] = o.s;
}

// ---------------------------------------------------------------------------
// W [1024 k][1024 n] f32 -> Wt [n][k] bf16 (4 matrices via blockIdx.z)
// z==0 (Wq) scaled by SCEXP so QK^T scores arrive in exp2 domain.
// ---------------------------------------------------------------------------
__global__ __launch_bounds__(256) void wcvt(const float* __restrict__ W0, const float* __restrict__ W1,
                                            const float* __restrict__ W2, const float* __restrict__ W3,
                                            unsigned short* __restrict__ T0, unsigned short* __restrict__ T1,
                                            unsigned short* __restrict__ T2, unsigned short* __restrict__ T3) {
    const float* W = blockIdx.z == 0 ? W0 : blockIdx.z == 1 ? W1 : blockIdx.z == 2 ? W2 : W3;
    unsigned short* T = blockIdx.z == 0 ? T0 : blockIdx.z == 1 ? T1 : blockIdx.z == 2 ? T2 : T3;
    const float sc = (blockIdx.z == 0) ? SCEXP : 1.f;
    __shared__ float Ls[64][65];
    const int tid = threadIdx.x;
    const int n0 = blockIdx.x * 64, k0 = blockIdx.y * 64;
#pragma unroll
    for (int i = 0; i < 4; ++i) {
        int q = tid + i * 256; int k = q >> 4, c = q & 15;
        f32x4 v = *(const f32x4*)&W[(size_t)(k0 + k) * 1024 + n0 + c * 4];
        Ls[k][c * 4 + 0] = v[0]; Ls[k][c * 4 + 1] = v[1];
        Ls[k][c * 4 + 2] = v[2]; Ls[k][c * 4 + 3] = v[3];
    }
    __syncthreads();
#pragma unroll
    for (int i = 0; i < 2; ++i) {
        int q = tid + i * 256; int n = q >> 3, c = q & 7;
        short8 ov;
#pragma unroll
        for (int j = 0; j < 8; ++j) ov[j] = (short)f2b(Ls[c * 8 + j][n] * sc);
        *(short8*)&T[(size_t)(n0 + n) * 1024 + k0 + c * 8] = ov;
    }
}

// ---------------------------------------------------------------------------
// V (b,h,s,e) bf16 -> Vt (b,h,e,s) bf16, 64x64 tiles
// ---------------------------------------------------------------------------
__global__ __launch_bounds__(256) void vtr(const unsigned short* __restrict__ V,
                                           unsigned short* __restrict__ Vt) {
    __shared__ __align__(16) unsigned short Ls[64][80];
    const int tid = threadIdx.x;
    const int s0 = blockIdx.x * 64;
    const size_t base = (size_t)blockIdx.y * SEQ * 64;
#pragma unroll
    for (int i = 0; i < 2; ++i) {
        int q = tid + i * 256; int s = q >> 3, c = q & 7;
        *(short8*)&Ls[s][c * 8] = *(const short8*)&V[base + (size_t)(s0 + s) * 64 + c * 8];
    }
    __syncthreads();
#pragma unroll
    for (int i = 0; i < 2; ++i) {
        int q = tid + i * 256; int e = q >> 3, c = q & 7;
        short8 ov;
#pragma unroll
        for (int j = 0; j < 8; ++j) ov[j] = (short)Ls[c * 8 + j][e];
        *(short8*)&Vt[base + (size_t)e * SEQ + s0 + c * 8] = ov;
    }
}

// ---------------------------------------------------------------------------
// GEMM: Y = A[4096][1024] @ Wt^T + bias. 128x128 tile, BK=32, 4 waves.
// MODE 0: fp32 row-major out (N=1024), bias b0.
// MODE 1: fused QKV (N=3072): block-uniform which=n0>>10 selects bias b0/b1/b2
//         (b0 scaled by SCEXP) and scatter chunk; bf16 scatter to (b,h,s,e).
// ---------------------------------------------------------------------------
#define CHE ((size_t)4096 * 1024)   // elems per activation chunk

template <int MODE>
__global__ __launch_bounds__(256) void gemm_mfma(const unsigned short* __restrict__ Ab,
                                                 const unsigned short* __restrict__ Bt,
                                                 const float* __restrict__ b0,
                                                 const float* __restrict__ b1,
                                                 const float* __restrict__ b2,
                                                 void* __restrict__ Yp) {
    __shared__ __align__(16) char AsB[8192];
    __shared__ __align__(16) char BsB[8192];
    const int tid = threadIdx.x;
    const int w = tid >> 6, l = tid & 63, lo = l & 15, hi = l >> 4;
    const int m0 = blockIdx.y * 128, n0 = blockIdx.x * 128;
    const int wm = (w & 1) * 64, wn = (w >> 1) * 64;
    const int which = (MODE == 1) ? (n0 >> 10) : 0;
    const float* biasp = which == 0 ? b0 : which == 1 ? b1 : b2;
    const float bsc = (MODE == 1 && which == 0) ? SCEXP : 1.f;

    f32x4 acc[4][4];
#pragma unroll
    for (int i = 0; i < 4; ++i)
#pragma unroll
        for (int j = 0; j < 4; ++j) acc[i][j] = f32x4{0.f, 0.f, 0.f, 0.f};

    const int cm = tid >> 2, cc = tid & 3;
    short8 fa8[2], fb[2];
    auto FETCH = [&](int kk) {
#pragma unroll
        for (int i = 0; i < 2; ++i) {
            int m = cm + 64 * i;
            fa8[i] = *(const short8*)&Ab[(size_t)(m0 + m) * 1024 + kk + cc * 8];
            fb[i] = *(const short8*)&Bt[(size_t)(n0 + m) * 1024 + kk + cc * 8];
        }
    };

    FETCH(0);
    for (int k0 = 0; k0 < 1024; k0 += 32) {
#pragma unroll
        for (int i = 0; i < 2; ++i) {
            int m = cm + 64 * i;
            int dst = (m * 64 + cc * 16) ^ ((m & 7) << 4);
            *(short8*)(AsB + dst) = fa8[i];
            *(short8*)(BsB + dst) = fb[i];
        }
        __syncthreads();
        if (k0 + 32 < 1024) FETCH(k0 + 32);

        short8 af_[4], bf_[4];
#pragma unroll
        for (int t = 0; t < 4; ++t) {
            int r = wm + t * 16 + lo;
            af_[t] = *(const short8*)(AsB + ((r * 64 + hi * 16) ^ ((r & 7) << 4)));
            int rn = wn + t * 16 + lo;
            bf_[t] = *(const short8*)(BsB + ((rn * 64 + hi * 16) ^ ((rn & 7) << 4)));
        }
        __builtin_amdgcn_s_setprio(1);
#pragma unroll
        for (int mt = 0; mt < 4; ++mt)
#pragma unroll
            for (int nt = 0; nt < 4; ++nt)
                acc[mt][nt] = __builtin_amdgcn_mfma_f32_16x16x32_bf16(af_[mt], bf_[nt], acc[mt][nt], 0, 0, 0);
        __builtin_amdgcn_s_setprio(0);
        __syncthreads();
    }

    float bv[4];
#pragma unroll
    for (int nt = 0; nt < 4; ++nt)
        bv[nt] = biasp[(n0 & 1023) + wn + nt * 16 + lo] * bsc;
#pragma unroll
    for (int mt = 0; mt < 4; ++mt)
#pragma unroll
        for (int nt = 0; nt < 4; ++nt)
#pragma unroll
            for (int r = 0; r < 4; ++r) {
                float v = acc[mt][nt][r] + bv[nt];
                int m = m0 + wm + mt * 16 + hi * 4 + r;
                int nloc = (n0 & 1023) + wn + nt * 16 + lo;
                if (MODE == 1) {
                    int b = m >> 11, s = m & 2047, hh = nloc >> 6, e = nloc & 63;
                    ((unsigned short*)Yp)[(size_t)which * CHE + (size_t)((b * 16 + hh) * SEQ + s) * 64 + e] = f2b(v);
                } else {
                    ((float*)Yp)[(size_t)m * 1024 + nloc] = v;
                }
            }
}

// ---------------------------------------------------------------------------
// Flash attention, bf16 MFMA, exp2-domain softmax (Q pre-scaled by SCEXP).
// Round 10: 512 thr = 8 waves, QBLK=128 (16 q rows/wave), KVBLK=64,
// DOUBLE-BUFFERED K/V LDS, ONE barrier per K-tile.
// Grid (SEQ/128, B*H). Swapped QK^T -> stats lane-local. Defer-max (THR=8).
// Masked = -2e30 (< m_init -1e30: fully-masked tiles give exact p=0).
// Dbuf safety: iter kv reads buf[kv&1] only; writes tile kv+1 into buf[cur^1],
// whose last reads finished before the PREVIOUS barrier.
// ---------------------------------------------------------------------------
__global__ __launch_bounds__(512) void attn_mfma(const unsigned short* __restrict__ Qg,
                                                 const unsigned short* __restrict__ Kg,
                                                 const unsigned short* __restrict__ Vtg,
                                                 const float* __restrict__ mask,
                                                 unsigned short* __restrict__ Og) {
    __shared__ __align__(16) char KsB[2][8192];
    __shared__ __align__(16) char VsB[2][8192];
    __shared__ __align__(16) char PsB[16384];   // 8 waves x 2KB
    const int tid = threadIdx.x;
    const int w = tid >> 6, l = tid & 63, lo = l & 15, hi = l >> 4;
    const int qt = blockIdx.x, bh = blockIdx.y, b = bh >> 4, h = bh & 15;

    const unsigned short* Qp = Qg + ((size_t)bh * SEQ + qt * 128 + w * 16 + lo) * 64;
    const short8 qf0 = *(const short8*)(Qp + hi * 8);
    const short8 qf1 = *(const short8*)(Qp + 32 + hi * 8);
    const unsigned short* Kb = Kg + (size_t)bh * SEQ * 64;
    const unsigned short* Vb = Vtg + (size_t)bh * 64 * SEQ;
    const float* mrow = mask + (size_t)b * SEQ * SEQ + (size_t)(qt * 128 + w * 16 + lo) * SEQ;
    char* PsW = PsB + w * 2048;

    float m_run = -1e30f, l_run = 0.f;
    const float MASKED = -2e30f;
    f32x4 acc[4];
#pragma unroll
    for (int nt = 0; nt < 4; ++nt) acc[nt] = f32x4{0.f, 0.f, 0.f, 0.f};

    // staging: one K row-chunk + one V row-chunk per thread (64 rows x 8 chunks)
    const int sk = tid >> 3, scol = tid & 7;
    const int sdst = (sk * 128 + scol * 16) ^ ((sk & 7) << 4);
    short8 pk, pv;
    f32x4 pm[4];
    auto FETCH = [&](int kv) {
        pk = *(const short8*)&Kb[(size_t)(kv * 64 + sk) * 64 + scol * 8];
        pv = *(const short8*)&Vb[(size_t)sk * SEQ + kv * 64 + scol * 8];
#pragma unroll
        for (int kt = 0; kt < 4; ++kt)
            pm[kt] = *(const f32x4*)&mrow[kv * 64 + kt * 16 + hi * 4];
    };

    FETCH(0);
    *(short8*)(KsB[0] + sdst) = pk;
    *(short8*)(VsB[0] + sdst) = pv;
    __syncthreads();

    for (int kv = 0; kv < 32; ++kv) {
        const int cur = kv & 1;
        const char* Kc = KsB[cur];
        const char* Vc = VsB[cur];
        f32x4 mv[4];
#pragma unroll
        for (int kt = 0; kt < 4; ++kt) mv[kt] = pm[kt];
        if (kv + 1 < 32) FETCH(kv + 1);   // global loads overlap compute below

        // St[key][q] = K . Q^T (already exp2-scaled via Q)
        f32x4 st[4];
        __builtin_amdgcn_s_setprio(1);
#pragma unroll
        for (int kt = 0; kt < 4; ++kt) {
            int r = kt * 16 + lo;
            short8 kf0 = *(const short8*)(Kc + ((r * 128 + hi * 16) ^ ((lo & 7) << 4)));
            short8 kf1 = *(const short8*)(Kc + ((r * 128 + 64 + hi * 16) ^ ((lo & 7) << 4)));
            f32x4 z = {0.f, 0.f, 0.f, 0.f};
            z = __builtin_amdgcn_mfma_f32_16x16x32_bf16(kf0, qf0, z, 0, 0, 0);
            st[kt] = __builtin_amdgcn_mfma_f32_16x16x32_bf16(kf1, qf1, z, 0, 0, 0);
        }
        __builtin_amdgcn_s_setprio(0);

        // mask select; local max
        float pmax = MASKED;
#pragma unroll
        for (int kt = 0; kt < 4; ++kt)
#pragma unroll
            for (int r = 0; r < 4; ++r) {
                float sv = (mv[kt][r] == 0.f) ? MASKED : st[kt][r];
                st[kt][r] = sv;
                pmax = fmaxf(pmax, sv);
            }
        pmax = fmaxf(pmax, __shfl_xor(pmax, 16, 64));
        pmax = fmaxf(pmax, __shfl_xor(pmax, 32, 64));

        // defer-max: only rescale when a lane's tile-max exceeds m_run + 8
        if (!__all(pmax <= m_run + 8.f)) {
            float mnew = fmaxf(m_run, pmax);
            float scf = __builtin_amdgcn_exp2f(m_run - mnew);
            l_run *= scf;
            float scr[4];
#pragma unroll
            for (int r = 0; r < 4; ++r) scr[r] = __shfl(scf, (hi << 2) + r, 64);
#pragma unroll
            for (int nt = 0; nt < 4; ++nt)
#pragma unroll
                for (int r = 0; r < 4; ++r) acc[nt][r] *= scr[r];
            m_run = mnew;
        }

        // p = exp2(sv - m), sum, pack (hw cvt_pk)
        float sum = 0.f;
        unsigned wpk[4][2];
#pragma unroll
        for (int kt = 0; kt < 4; ++kt) {
            float p0 = __builtin_amdgcn_exp2f(st[kt][0] - m_run);
            float p1 = __builtin_amdgcn_exp2f(st[kt][1] - m_run);
            float p2 = __builtin_amdgcn_exp2f(st[kt][2] - m_run);
            float p3 = __builtin_amdgcn_exp2f(st[kt][3] - m_run);
            sum += (p0 + p1) + (p2 + p3);
            wpk[kt][0] = pk2(p0, p1);
            wpk[kt][1] = pk2(p2, p3);
        }
        sum += __shfl_xor(sum, 16, 64);
        sum += __shfl_xor(sum, 32, 64);
        l_run += sum;

        // P rows -> per-wave swizzled LDS -> PV A-frags (wave-private buffer)
#pragma unroll
        for (int kt = 0; kt < 4; ++kt) {
            int d0 = (lo * 128 + kt * 32 + hi * 8) ^ ((lo & 7) << 4);
            *(unsigned*)(PsW + d0) = wpk[kt][0];
            *(unsigned*)(PsW + d0 + 4) = wpk[kt][1];
        }
        short8 pa0 = *(const short8*)(PsW + ((lo * 128 + hi * 16) ^ ((lo & 7) << 4)));
        short8 pa1 = *(const short8*)(PsW + ((lo * 128 + 64 + hi * 16) ^ ((lo & 7) << 4)));
        __builtin_amdgcn_s_setprio(1);
#pragma unroll
        for (int nt = 0; nt < 4; ++nt) {
            int r = nt * 16 + lo;
            short8 v0 = *(const short8*)(Vc + ((r * 128 + hi * 16) ^ ((lo & 7) << 4)));
            short8 v1 = *(const short8*)(Vc + ((r * 128 + 64 + hi * 16) ^ ((lo & 7) << 4)));
            acc[nt] = __builtin_amdgcn_mfma_f32_16x16x32_bf16(pa0, v0, acc[nt], 0, 0, 0);
            acc[nt] = __builtin_amdgcn_mfma_f32_16x16x32_bf16(pa1, v1, acc[nt], 0, 0, 0);
        }
        __builtin_amdgcn_s_setprio(0);

        // stage tile kv+1 into the other buffer, then the single barrier
        if (kv + 1 < 32) {
            *(short8*)(KsB[cur ^ 1] + sdst) = pk;
            *(short8*)(VsB[cur ^ 1] + sdst) = pv;
        }
        __syncthreads();
    }

    float lr[4];
#pragma unroll
    for (int r = 0; r < 4; ++r) lr[r] = 1.f / __shfl(l_run, (hi << 2) + r, 64);
#pragma unroll
    for (int nt = 0; nt < 4; ++nt)
#pragma unroll
        for (int r = 0; r < 4; ++r) {
            int qg2 = qt * 128 + w * 16 + hi * 4 + r;
            Og[(size_t)(b * SEQ + qg2) * 1024 + h * 64 + nt * 16 + lo] = f2b(acc[nt][r] * lr[r]);
        }
}

// ---------------------------------------------------------------------------
extern "C" void kernel_launch(void* const* d_in, const int* in_sizes, int n_in,
                              void* d_out, int out_size, void* d_ws, size_t ws_size,
                              hipStream_t stream) {
    const float* x  = (const float*)d_in[0];
    const float* kg = (const float*)d_in[1];
    const float* Wq = (const float*)d_in[2];
    const float* bq = (const float*)d_in[3];
    const float* Wk = (const float*)d_in[4];
    const float* bk = (const float*)d_in[5];
    const float* Wv = (const float*)d_in[6];
    const float* bv = (const float*)d_in[7];
    const float* Wo = (const float*)d_in[8];
    const float* bo = (const float*)d_in[9];

    unsigned short* ws = (unsigned short*)d_ws;
    const size_t WSZ = 1024 * 1024;
    unsigned short* wtq = ws;                 // [3072][1024] concat q,k,v
    unsigned short* wtk = ws + WSZ;
    unsigned short* wtv = ws + 2 * WSZ;
    unsigned short* wto = ws + 3 * WSZ;
    unsigned short* xb  = ws + 4 * WSZ;       // x bf16
    unsigned short* qb  = ws + 8 * WSZ;       // q,k,v chunks (scatter target base)
    unsigned short* kb  = qb + CHE;
    unsigned short* vb  = kb + CHE;
    unsigned short* vt  = vb + CHE;
    unsigned short* ob  = vt + CHE;

    xcvt<<<2048, 256, 0, stream>>>(x, xb);
    wcvt<<<dim3(16, 16, 4), 256, 0, stream>>>(Wq, Wk, Wv, Wo, wtq, wtk, wtv, wto);

    gemm_mfma<1><<<dim3(24, 32), 256, 0, stream>>>(xb, wtq, bq, bk, bv, qb);

    vtr<<<dim3(32, 32), 256, 0, stream>>>(vb, vt);

    attn_mfma<<<dim3(16, 32), 512, 0, stream>>>(qb, kb, vt, kg, ob);

    gemm_mfma<0><<<dim3(8, 32), 256, 0, stream>>>(ob, wto, bo, bo, bo, d_out);
}